// Round 3
// baseline (411.134 us; speedup 1.0000x reference)
//
#include <hip/hip_runtime.h>

typedef short bf16x8 __attribute__((ext_vector_type(8)));
typedef float f32x4 __attribute__((ext_vector_type(4)));

#define ELLK 32
#define OCAP 4096
#define CSTRIDE 16  // ints between degree counters (64B apart): no same-line counter aliasing

static __device__ __forceinline__ float4 f4zero() { return make_float4(0.f, 0.f, 0.f, 0.f); }

// round-to-nearest-even f32 -> bf16
static __device__ __forceinline__ unsigned short f2bf(float f) {
  unsigned u = __float_as_uint(f);
  u += 0x7FFFu + ((u >> 16) & 1u);
  return (unsigned short)(u >> 16);
}
// packed pair of bf16 (low = first elem) -> float2
static __device__ __forceinline__ float2 bf2x2(unsigned u) {
  float2 r;
  r.x = __uint_as_float(u << 16);
  r.y = __uint_as_float(u & 0xFFFF0000u);
  return r;
}

// ---------- setup: zero spread counters/ocount + transpose weights to bf16 Wt[n][k] ----------
__global__ void k_setup(const float* __restrict__ W1, const float* __restrict__ Wmu,
                        const float* __restrict__ Wlv, unsigned short* __restrict__ Wt1,
                        unsigned short* __restrict__ Wt2, uint4* __restrict__ cntz,
                        int* __restrict__ ocount, int nz4, int nbz) {
  int b = blockIdx.x;
  if (b < nbz) {
    int i = b * 256 + threadIdx.x;
    if (i < nz4) cntz[i] = make_uint4(0u, 0u, 0u, 0u);
    if (b == 0 && threadIdx.x == 0) *ocount = 0;
  } else {
    int id = (b - nbz) * 256 + threadIdx.x;  // 0..32767
    if (id < 16384) {
      int nn = id >> 7, k = id & 127;
      Wt1[id] = f2bf(W1[k * 128 + nn]);
    } else {
      int id2 = id - 16384;
      int nn = id2 >> 7, k = id2 & 127;
      float v = (nn < 64) ? Wmu[k * 64 + nn] : Wlv[k * 64 + (nn - 64)];
      Wt2[id2] = f2bf(v);
    }
  }
}

// ---------- ELL fill (TRANSPOSED layout ell[pos][n]): 4 edges/thread for atomic MLP ----------
__global__ void k_fill(const int* __restrict__ ei, int* __restrict__ cnt,
                       int* __restrict__ ell, int2* __restrict__ ovf,
                       int* __restrict__ ocount, int E, int n) {
  int e0 = blockIdx.x * 1024 + threadIdx.x;
  int ss[4], dd[4], pos[4];
  bool ok[4];
#pragma unroll
  for (int k = 0; k < 4; ++k) {  // 8 independent loads in flight
    int e = e0 + k * 256;
    ok[k] = (e < E);
    ss[k] = ok[k] ? ei[e] : 0;
    dd[k] = ok[k] ? ei[E + e] : 0;
  }
#pragma unroll
  for (int k = 0; k < 4; ++k)  // 4 independent atomics in flight
    pos[k] = ok[k] ? atomicAdd(&cnt[(size_t)dd[k] * CSTRIDE], 1) : ELLK;
#pragma unroll
  for (int k = 0; k < 4; ++k) {
    if (!ok[k]) continue;
    if (pos[k] < ELLK) {
      __builtin_nontemporal_store(ss[k], &ell[(size_t)pos[k] * n + dd[k]]);
    } else {
      int o = atomicAdd(ocount, 1);
      if (o < OCAP) ovf[o] = make_int2(dd[k], ss[k]);
    }
  }
}

// ---------- dnorm: dnorm[i] = rsqrt(deg_i), mflag[i] = min(c,32) | ovf_bit; zero pad rows ----------
__global__ void k_dnorm(const int* __restrict__ cnt, float* __restrict__ dnorm,
                        unsigned* __restrict__ mflag, unsigned* __restrict__ A,
                        unsigned* __restrict__ H, int n) {
  if (blockIdx.x == 0 && threadIdx.x < 128) {  // zero-row at index n (gather pad target)
    int t = threadIdx.x;
    if (t < 64) A[(size_t)n * 64 + t] = 0u;
    else        H[(size_t)n * 64 + (t - 64)] = 0u;
  }
  int i = blockIdx.x * 256 + threadIdx.x;
  if (i >= n) return;
  int c = cnt[(size_t)i * CSTRIDE];
  dnorm[i] = rsqrtf((float)(c + 1));
  int m = (c < ELLK) ? c : ELLK;
  mflag[i] = (unsigned)m | ((c > ELLK) ? 0x80000000u : 0u);
}

// ---------- GEMM1 (MFMA): A = bf16(dnorm[i] * (x @ W1)) via Wt1[n][k] ----------
__global__ __launch_bounds__(256) void k_gemm1(
    const float* __restrict__ x, const unsigned short* __restrict__ Wt,
    const float* __restrict__ dnorm, unsigned short* __restrict__ A, int n) {
  __shared__ unsigned short Wl[128 * 136];  // padded rows: +8 bf16
  __shared__ unsigned short Xl[64 * 136];
  const int tid = threadIdx.x;
  const int row0 = blockIdx.x * 64;
  {
    const uint4* Wg = (const uint4*)Wt;
#pragma unroll
    for (int i = 0; i < 8; ++i) {
      int idx = tid + i * 256;  // 0..2047
      int r = idx >> 4, c = idx & 15;
      *(uint4*)&Wl[r * 136 + c * 8] = Wg[r * 16 + c];
    }
  }
  {
#pragma unroll
    for (int i = 0; i < 8; ++i) {
      int idx = tid + i * 256;  // 0..2047
      int r = idx >> 5, c = idx & 31;
      int gi = row0 + r;
      float4 v = (gi < n) ? ((const float4*)x)[(size_t)gi * 32 + c] : f4zero();
      ushort4 p;
      p.x = f2bf(v.x); p.y = f2bf(v.y); p.z = f2bf(v.z); p.w = f2bf(v.w);
      *(ushort4*)&Xl[r * 136 + c * 4] = p;
    }
  }
  __syncthreads();

  const int wave = tid >> 6, lane = tid & 63;
  const int li = lane & 15, quad = lane >> 4;
  const int m0 = wave * 16;
  f32x4 acc[8];
#pragma unroll
  for (int t = 0; t < 8; ++t) acc[t] = (f32x4){0.f, 0.f, 0.f, 0.f};

#pragma unroll
  for (int kk = 0; kk < 4; ++kk) {
    int ko = kk * 32 + quad * 8;
    bf16x8 a = *(const bf16x8*)&Xl[(m0 + li) * 136 + ko];
#pragma unroll
    for (int nt = 0; nt < 8; ++nt) {
      bf16x8 b = *(const bf16x8*)&Wl[(nt * 16 + li) * 136 + ko];
      acc[nt] = __builtin_amdgcn_mfma_f32_16x16x32_bf16(a, b, acc[nt], 0, 0, 0);
    }
  }
  // per-row degree scale, then repack through LDS for coalesced 16B stores
  float dn[4];
#pragma unroll
  for (int r = 0; r < 4; ++r) {
    int gi = row0 + m0 + quad * 4 + r;
    dn[r] = (gi < n) ? dnorm[gi] : 0.f;
  }
  __syncthreads();
#pragma unroll
  for (int nt = 0; nt < 8; ++nt)
#pragma unroll
    for (int r = 0; r < 4; ++r)
      Xl[(m0 + quad * 4 + r) * 136 + nt * 16 + li] = f2bf(acc[nt][r] * dn[r]);
  __syncthreads();
  {
    uint4* A4 = (uint4*)A;
#pragma unroll
    for (int i = 0; i < 4; ++i) {
      int idx = tid + i * 256;  // 0..1023
      int r = idx >> 4, c = idx & 15;
      int gi = row0 + r;
      if (gi < n) A4[(size_t)gi * 16 + c] = *(uint4*)&Xl[r * 136 + c * 8];
    }
  }
}

// ---------- SpMM aggregation, XCD channel-sliced ----------
// slice = bid & 3 -> with round-robin block->XCD dispatch, XCD j always serves slice j&3:
// per-XCD gather working set = 6.4 MB (vs 25.6) -> L2-resident gathers.
// wave = 4 nodes x 16 lanes (32 channels = 64B per node-slice, one request per edge-slice).
// pads redirect to zero-row n; index/meta loads are non-temporal (don't evict the slice).
template <bool EPI_RELU>
__global__ __launch_bounds__(256) void k_spmm(
    const unsigned* __restrict__ mflag, const float* __restrict__ dnorm,
    const int* __restrict__ ell, const int2* __restrict__ ovf,
    const int* __restrict__ ocount, const unsigned* __restrict__ S,
    unsigned* __restrict__ D, const float2* __restrict__ bias, int n) {
  const int bid = blockIdx.x;
  const int s = bid & 3;   // channel slice (pinned per XCD via dispatch round-robin)
  const int g = bid >> 2;  // node group (16 nodes per block)
  const int tid = threadIdx.x;
  const int lane = tid & 63;
  const int nsub = lane >> 4;   // node within wave (0..3)
  const int csub = lane & 15;   // packed-uint within slice (0..15)
  const int node = g * 16 + (tid >> 6) * 4 + nsub;
  if (node >= n) return;
  const int col = s * 16 + csub;

  unsigned mf = __builtin_nontemporal_load(&mflag[node]);
  int m = (int)(mf & 0xFFFFu);
  float dsd = __builtin_nontemporal_load(&dnorm[node]);
  float2 acc = bf2x2(S[(size_t)node * 64 + col]);  // own row (self-loop term)

  const int* ep = ell + node;  // plane stride = n
  int nbt = (m + 7) >> 3;
  for (int b = 0; b < nbt; ++b) {
    int j0 = b * 8;
    int idx[8];
#pragma unroll
    for (int k = 0; k < 8; ++k)
      idx[k] = __builtin_nontemporal_load(&ep[(size_t)(j0 + k) * n]);
#pragma unroll
    for (int k = 0; k < 8; ++k) idx[k] = (j0 + k < m) ? idx[k] : n;  // pads -> zero row
    unsigned u[8];
#pragma unroll
    for (int k = 0; k < 8; ++k) u[k] = S[(size_t)idx[k] * 64 + col];  // 32 reqs in flight/wave
#pragma unroll
    for (int k = 0; k < 8; ++k) {
      float2 f = bf2x2(u[k]);
      acc.x += f.x;
      acc.y += f.y;
    }
  }
  if (mf & 0x80000000u) {  // pathological high-degree nodes: scan tiny overflow list
    int oc = *ocount;
    if (oc > OCAP) oc = OCAP;
    for (int k = 0; k < oc; ++k) {
      int2 e = ovf[k];
      if (e.x == node) {
        float2 u0 = bf2x2(S[(size_t)e.y * 64 + col]);
        acc.x += u0.x;
        acc.y += u0.y;
      }
    }
  }
  float2 o;
  if (EPI_RELU) {
    float2 b = bias[col];
    // out1 = dis_i*acc + b; store H_bar = dis_i * relu(out1) (pre-scaled for layer 2)
    o.x = dsd * fmaxf(fmaf(dsd, acc.x, b.x), 0.f);
    o.y = dsd * fmaxf(fmaf(dsd, acc.y, b.y), 0.f);
  } else {
    o.x = dsd * acc.x;
    o.y = dsd * acc.y;
  }
  unsigned pk = (unsigned)f2bf(o.x) | ((unsigned)f2bf(o.y) << 16);
  D[(size_t)node * 64 + col] = pk;
}

// ---------- GEMM2 (MFMA): out = [G@Wmu+bmu | G@Wlv+blv] via Wt2[n][k] ----------
__global__ __launch_bounds__(256) void k_gemm2_mfma(
    const unsigned short* __restrict__ G, const unsigned short* __restrict__ Wt,
    const float* __restrict__ bmu, const float* __restrict__ blv,
    float* __restrict__ out, int n) {
  __shared__ unsigned short Wl[128 * 136];
  __shared__ unsigned short Xl[64 * 136];
  const int tid = threadIdx.x;
  const int row0 = blockIdx.x * 64;
  {
    const uint4* Wg = (const uint4*)Wt;
#pragma unroll
    for (int i = 0; i < 8; ++i) {
      int idx = tid + i * 256;
      int r = idx >> 4, c = idx & 15;
      *(uint4*)&Wl[r * 136 + c * 8] = Wg[r * 16 + c];
    }
  }
  {
    const uint4* Gg = (const uint4*)G;
#pragma unroll
    for (int i = 0; i < 4; ++i) {
      int idx = tid + i * 256;  // 0..1023
      int r = idx >> 4, c = idx & 15;
      int gi = row0 + r;
      uint4 v = (gi < n) ? Gg[(size_t)gi * 16 + c] : make_uint4(0, 0, 0, 0);
      *(uint4*)&Xl[r * 136 + c * 8] = v;
    }
  }
  __syncthreads();

  const int wave = tid >> 6, lane = tid & 63;
  const int li = lane & 15, quad = lane >> 4;
  const int m0 = wave * 16;

  float bias[8];
#pragma unroll
  for (int nt = 0; nt < 8; ++nt) {
    int c = nt * 16 + li;
    bias[nt] = (c < 64) ? bmu[c] : blv[c - 64];
  }

  f32x4 acc[8];
#pragma unroll
  for (int t = 0; t < 8; ++t) acc[t] = (f32x4){0.f, 0.f, 0.f, 0.f};

#pragma unroll
  for (int kk = 0; kk < 4; ++kk) {
    int ko = kk * 32 + quad * 8;
    bf16x8 a = *(const bf16x8*)&Xl[(m0 + li) * 136 + ko];
#pragma unroll
    for (int nt = 0; nt < 8; ++nt) {
      bf16x8 b = *(const bf16x8*)&Wl[(nt * 16 + li) * 136 + ko];
      acc[nt] = __builtin_amdgcn_mfma_f32_16x16x32_bf16(a, b, acc[nt], 0, 0, 0);
    }
  }
#pragma unroll
  for (int nt = 0; nt < 8; ++nt) {
    int col = nt * 16 + li;
#pragma unroll
    for (int r = 0; r < 4; ++r) {
      int gi = row0 + m0 + quad * 4 + r;
      if (gi < n) {
        float v = acc[nt][r] + bias[nt];
        if (col < 64) out[(size_t)gi * 64 + col] = v;              // mu
        else          out[(size_t)(n + gi) * 64 + (col - 64)] = v; // logvar
      }
    }
  }
}

extern "C" void kernel_launch(void* const* d_in, const int* in_sizes, int n_in,
                              void* d_out, int out_size, void* d_ws, size_t ws_size,
                              hipStream_t stream) {
  const float* x   = (const float*)d_in[0];
  const int*   ei  = (const int*)d_in[1];   // [2, E], row0 = src, row1 = dst
  const float* W1  = (const float*)d_in[3];
  const float* b1  = (const float*)d_in[4];
  const float* Wmu = (const float*)d_in[5];
  const float* bmu = (const float*)d_in[6];
  const float* Wlv = (const float*)d_in[7];
  const float* blv = (const float*)d_in[8];
  float* out = (float*)d_out;

  const int n = in_sizes[0] / 128;
  const int E = in_sizes[1] / 2;

  // workspace layout (float units)
  float* ws = (float*)d_ws;
  size_t p = 0;
  int* cnt    = (int*)(ws + p); p += (size_t)n * CSTRIDE;  // spread counters (64B apart)
  int* ocount = (int*)(ws + p); p += 1;
  p = (p + 3) & ~(size_t)3;  // 16B align
  int* ell    = (int*)(ws + p); p += (size_t)n * ELLK;     // TRANSPOSED: [ELLK][n]
  int2* ovf   = (int2*)(ws + p); p += (size_t)OCAP * 2;
  unsigned* A = (unsigned*)(ws + p); p += (size_t)(n + 1) * 64;  // +1: zero pad row
  unsigned* H = (unsigned*)(ws + p); p += (size_t)(n + 1) * 64;
  unsigned* G = (unsigned*)(ws + p); p += (size_t)n * 64;
  unsigned short* Wt1 = (unsigned short*)(ws + p); p += 8192;  // 128x128 bf16
  unsigned short* Wt2 = (unsigned short*)(ws + p); p += 8192;
  float* dnorm    = (float*)(ws + p); p += n;
  unsigned* mflag = (unsigned*)(ws + p); p += n;

  int nz4  = (n * CSTRIDE) / 4;        // uint4 count for counter zeroing
  int nbz  = (nz4 + 255) / 256;
  int eb   = (E + 1023) / 1024;        // 4 edges per thread
  int gblk = (n + 63) / 64;
  int nb   = (n + 255) / 256;
  int sblk = ((n + 15) / 16) * 4;      // 16 nodes per block x 4 channel slices

  // 1) zero counters/ocount + weight transpose
  k_setup<<<nbz + 128, 256, 0, stream>>>(W1, Wmu, Wlv, Wt1, Wt2, (uint4*)cnt, ocount, nz4, nbz);
  // 2) ELL build (transposed planes, 4-deep atomic pipelining)
  k_fill<<<eb, 256, 0, stream>>>(ei, cnt, ell, ovf, ocount, E, n);
  // 3) degree norms + packed counts + zero pad rows
  k_dnorm<<<nb, 256, 0, stream>>>(cnt, dnorm, mflag, A, H, n);
  // 4) A = bf16(dis_i * (x @ W1)) -- rows pre-scaled
  k_gemm1<<<gblk, 256, 0, stream>>>(x, Wt1, dnorm, (unsigned short*)A, n);
  // 5) layer 1: H = bf16(dis_i * relu(dis_i * sum + b1))  (pre-scaled for layer 2)
  k_spmm<true><<<sblk, 256, 0, stream>>>(mflag, dnorm, ell, ovf, ocount, A, H,
                                         (const float2*)b1, n);
  // 6) layer 2: G = bf16(dis_i * sum)
  k_spmm<false><<<sblk, 256, 0, stream>>>(mflag, dnorm, ell, ovf, ocount, H, G, nullptr, n);
  // 7) out = [G@Wmu+bmu | G@Wlv+blv]
  k_gemm2_mfma<<<gblk, 256, 0, stream>>>((const unsigned short*)G, Wt2, bmu, blv, out, n);
}

// Round 4
// 294.892 us; speedup vs baseline: 1.3942x; 1.3942x over previous
//
#include <hip/hip_runtime.h>

typedef short bf16x8 __attribute__((ext_vector_type(8)));
typedef float f32x4 __attribute__((ext_vector_type(4)));

#define ELLK 32
#define OCAP 4096
#define CSTRIDE 16  // ints between degree counters (64B apart): no same-line counter aliasing

static __device__ __forceinline__ float4 f4zero() { return make_float4(0.f, 0.f, 0.f, 0.f); }

// round-to-nearest-even f32 -> bf16
static __device__ __forceinline__ unsigned short f2bf(float f) {
  unsigned u = __float_as_uint(f);
  u += 0x7FFFu + ((u >> 16) & 1u);
  return (unsigned short)(u >> 16);
}
// packed pair of bf16 (low = first elem) -> float2
static __device__ __forceinline__ float2 bf2x2(unsigned u) {
  float2 r;
  r.x = __uint_as_float(u << 16);
  r.y = __uint_as_float(u & 0xFFFF0000u);
  return r;
}

// ---------- setup: zero counters/ocount/pad-rows + transpose weights to bf16 Wt[n][k] ----------
__global__ void k_setup(const float* __restrict__ W1, const float* __restrict__ Wmu,
                        const float* __restrict__ Wlv, unsigned short* __restrict__ Wt1,
                        unsigned short* __restrict__ Wt2, uint4* __restrict__ cntz,
                        int* __restrict__ ocount, unsigned* __restrict__ A,
                        unsigned* __restrict__ H, int nz4, int nbz, int n) {
  int b = blockIdx.x;
  if (b < nbz) {
    int i = b * 256 + threadIdx.x;
    if (i < nz4) cntz[i] = make_uint4(0u, 0u, 0u, 0u);
    if (b == 0) {
      int t = threadIdx.x;
      if (t == 0) *ocount = 0;
      if (t < 64) A[(size_t)n * 64 + t] = 0u;          // zero-row pad target (A)
      else if (t < 128) H[(size_t)n * 64 + (t - 64)] = 0u;  // zero-row pad target (H)
    }
  } else {
    int id = (b - nbz) * 256 + threadIdx.x;  // 0..32767
    if (id < 16384) {
      int nn = id >> 7, k = id & 127;
      Wt1[id] = f2bf(W1[k * 128 + nn]);
    } else {
      int id2 = id - 16384;
      int nn = id2 >> 7, k = id2 & 127;
      float v = (nn < 64) ? Wmu[k * 64 + nn] : Wlv[k * 64 + (nn - 64)];
      Wt2[id2] = f2bf(v);
    }
  }
}

// ---------- ELL fill (TRANSPOSED layout ell[pos][n]): 4 edges/thread for atomic MLP ----------
__global__ void k_fill(const int* __restrict__ ei, int* __restrict__ cnt,
                       int* __restrict__ ell, int2* __restrict__ ovf,
                       int* __restrict__ ocount, int E, int n) {
  int e0 = blockIdx.x * 1024 + threadIdx.x;
  int ss[4], dd[4], pos[4];
  bool ok[4];
#pragma unroll
  for (int k = 0; k < 4; ++k) {  // 8 independent loads in flight
    int e = e0 + k * 256;
    ok[k] = (e < E);
    ss[k] = ok[k] ? ei[e] : 0;
    dd[k] = ok[k] ? ei[E + e] : 0;
  }
#pragma unroll
  for (int k = 0; k < 4; ++k)  // 4 independent atomics in flight
    pos[k] = ok[k] ? atomicAdd(&cnt[(size_t)dd[k] * CSTRIDE], 1) : ELLK;
#pragma unroll
  for (int k = 0; k < 4; ++k) {
    if (!ok[k]) continue;
    if (pos[k] < ELLK) {
      __builtin_nontemporal_store(ss[k], &ell[(size_t)pos[k] * n + dd[k]]);
    } else {
      int o = atomicAdd(ocount, 1);
      if (o < OCAP) ovf[o] = make_int2(dd[k], ss[k]);
    }
  }
}

// ---------- GEMM1 (MFMA): A = bf16(dnorm[i] * (x @ W1)); also emits dnorm/mflag ----------
__global__ __launch_bounds__(256) void k_gemm1(
    const float* __restrict__ x, const unsigned short* __restrict__ Wt,
    const int* __restrict__ cnt, unsigned short* __restrict__ A,
    float* __restrict__ dnorm, unsigned* __restrict__ mflag, int n) {
  __shared__ unsigned short Wl[128 * 136];  // padded rows: +8 bf16
  __shared__ unsigned short Xl[64 * 136];
  __shared__ float dnl[64];
  const int tid = threadIdx.x;
  const int row0 = blockIdx.x * 64;
  {
    const uint4* Wg = (const uint4*)Wt;
#pragma unroll
    for (int i = 0; i < 8; ++i) {
      int idx = tid + i * 256;  // 0..2047
      int r = idx >> 4, c = idx & 15;
      *(uint4*)&Wl[r * 136 + c * 8] = Wg[r * 16 + c];
    }
  }
  {
#pragma unroll
    for (int i = 0; i < 8; ++i) {
      int idx = tid + i * 256;  // 0..2047
      int r = idx >> 5, c = idx & 31;
      int gi = row0 + r;
      float4 v = (gi < n) ? ((const float4*)x)[(size_t)gi * 32 + c] : f4zero();
      ushort4 p;
      p.x = f2bf(v.x); p.y = f2bf(v.y); p.z = f2bf(v.z); p.w = f2bf(v.w);
      *(ushort4*)&Xl[r * 136 + c * 4] = p;
    }
  }
  __syncthreads();

  // side product: dnorm/mflag for this block's rows (cnt is L2-hot after fill)
  if (tid < 64) {
    int gi = row0 + tid;
    float dn = 0.f;
    if (gi < n) {
      int c = cnt[(size_t)gi * CSTRIDE];
      dn = rsqrtf((float)(c + 1));
      dnorm[gi] = dn;
      int mm = (c < ELLK) ? c : ELLK;
      mflag[gi] = (unsigned)mm | ((c > ELLK) ? 0x80000000u : 0u);
    }
    dnl[tid] = dn;
  }

  const int wave = tid >> 6, lane = tid & 63;
  const int li = lane & 15, quad = lane >> 4;
  const int m0 = wave * 16;
  f32x4 acc[8];
#pragma unroll
  for (int t = 0; t < 8; ++t) acc[t] = (f32x4){0.f, 0.f, 0.f, 0.f};

#pragma unroll
  for (int kk = 0; kk < 4; ++kk) {
    int ko = kk * 32 + quad * 8;
    bf16x8 a = *(const bf16x8*)&Xl[(m0 + li) * 136 + ko];
#pragma unroll
    for (int nt = 0; nt < 8; ++nt) {
      bf16x8 b = *(const bf16x8*)&Wl[(nt * 16 + li) * 136 + ko];
      acc[nt] = __builtin_amdgcn_mfma_f32_16x16x32_bf16(a, b, acc[nt], 0, 0, 0);
    }
  }
  __syncthreads();  // MFMA reads of Xl done; dnl visible
  float dn[4];
#pragma unroll
  for (int r = 0; r < 4; ++r) dn[r] = dnl[m0 + quad * 4 + r];
#pragma unroll
  for (int nt = 0; nt < 8; ++nt)
#pragma unroll
    for (int r = 0; r < 4; ++r)
      Xl[(m0 + quad * 4 + r) * 136 + nt * 16 + li] = f2bf(acc[nt][r] * dn[r]);
  __syncthreads();
  {
    uint4* A4 = (uint4*)A;
#pragma unroll
    for (int i = 0; i < 4; ++i) {
      int idx = tid + i * 256;  // 0..1023
      int r = idx >> 4, c = idx & 15;
      int gi = row0 + r;
      if (gi < n) A4[(size_t)gi * 16 + c] = *(uint4*)&Xl[r * 136 + c * 8];
    }
  }
}

// ---------- SpMM aggregation over transposed ELL: pure row-sum, 16-deep straight-line ----------
// one 64-lane wave per node; lane = 2 channels (packed uint); full 256B rows (100% line use)
// pads redirect to L1-resident zero-row n; 16 index loads then 16 gathers all in flight
template <bool EPI_RELU>
__global__ __launch_bounds__(256) void k_spmm(
    const unsigned* __restrict__ mflag, const float* __restrict__ dnorm,
    const int* __restrict__ ell, const int2* __restrict__ ovf,
    const int* __restrict__ ocount, const unsigned* __restrict__ S,
    unsigned* __restrict__ D, const float2* __restrict__ bias, int n) {
  int wid = (blockIdx.x * blockDim.x + threadIdx.x) >> 6;
  if (wid >= n) return;
  int lane = threadIdx.x & 63;

  unsigned mf = mflag[wid];
  int m = (int)(mf & 0xFFFFu);
  float dsd = dnorm[wid];
  float2 acc = bf2x2(S[(size_t)wid * 64 + lane]);  // own row (self-loop term)

  const int* ep = ell + wid;  // plane stride = n
  {
    int idx[16];
#pragma unroll
    for (int k = 0; k < 16; ++k) idx[k] = ep[(size_t)k * n];  // wave-uniform loads
#pragma unroll
    for (int k = 0; k < 16; ++k) idx[k] = (k < m) ? idx[k] : n;  // pads -> zero row
    unsigned u[16];
#pragma unroll
    for (int k = 0; k < 16; ++k) u[k] = S[(size_t)idx[k] * 64 + lane];  // 16 gathers in flight
#pragma unroll
    for (int k = 0; k < 16; ++k) {
      float2 f = bf2x2(u[k]);
      acc.x += f.x;
      acc.y += f.y;
    }
  }
  if (m > 16) {  // rare tail (P[deg>16 | Poisson(8)] ~ 0.4%)
    for (int j0 = 16; j0 < m; j0 += 8) {
      int idx[8];
#pragma unroll
      for (int k = 0; k < 8; ++k) idx[k] = ep[(size_t)(j0 + k) * n];
#pragma unroll
      for (int k = 0; k < 8; ++k) idx[k] = (j0 + k < m) ? idx[k] : n;
      unsigned u[8];
#pragma unroll
      for (int k = 0; k < 8; ++k) u[k] = S[(size_t)idx[k] * 64 + lane];
#pragma unroll
      for (int k = 0; k < 8; ++k) {
        float2 f = bf2x2(u[k]);
        acc.x += f.x;
        acc.y += f.y;
      }
    }
  }
  if (mf & 0x80000000u) {  // pathological high-degree nodes: scan tiny overflow list
    int oc = *ocount;
    if (oc > OCAP) oc = OCAP;
    for (int k = 0; k < oc; ++k) {
      int2 e = ovf[k];
      if (e.x == wid) {
        float2 u0 = bf2x2(S[(size_t)e.y * 64 + lane]);
        acc.x += u0.x;
        acc.y += u0.y;
      }
    }
  }
  float2 o;
  if (EPI_RELU) {
    float2 b = bias[lane];
    // out1 = dis_i*acc + b; store H_bar = dis_i * relu(out1) (pre-scaled for layer 2)
    o.x = dsd * fmaxf(fmaf(dsd, acc.x, b.x), 0.f);
    o.y = dsd * fmaxf(fmaf(dsd, acc.y, b.y), 0.f);
  } else {
    o.x = dsd * acc.x;
    o.y = dsd * acc.y;
  }
  unsigned pk = (unsigned)f2bf(o.x) | ((unsigned)f2bf(o.y) << 16);
  D[(size_t)wid * 64 + lane] = pk;
}

// ---------- GEMM2 (MFMA): out = [G@Wmu+bmu | G@Wlv+blv] via Wt2[n][k] ----------
__global__ __launch_bounds__(256) void k_gemm2_mfma(
    const unsigned short* __restrict__ G, const unsigned short* __restrict__ Wt,
    const float* __restrict__ bmu, const float* __restrict__ blv,
    float* __restrict__ out, int n) {
  __shared__ unsigned short Wl[128 * 136];
  __shared__ unsigned short Xl[64 * 136];
  const int tid = threadIdx.x;
  const int row0 = blockIdx.x * 64;
  {
    const uint4* Wg = (const uint4*)Wt;
#pragma unroll
    for (int i = 0; i < 8; ++i) {
      int idx = tid + i * 256;
      int r = idx >> 4, c = idx & 15;
      *(uint4*)&Wl[r * 136 + c * 8] = Wg[r * 16 + c];
    }
  }
  {
    const uint4* Gg = (const uint4*)G;
#pragma unroll
    for (int i = 0; i < 4; ++i) {
      int idx = tid + i * 256;  // 0..1023
      int r = idx >> 4, c = idx & 15;
      int gi = row0 + r;
      uint4 v = (gi < n) ? Gg[(size_t)gi * 16 + c] : make_uint4(0, 0, 0, 0);
      *(uint4*)&Xl[r * 136 + c * 8] = v;
    }
  }
  __syncthreads();

  const int wave = tid >> 6, lane = tid & 63;
  const int li = lane & 15, quad = lane >> 4;
  const int m0 = wave * 16;

  float bias[8];
#pragma unroll
  for (int nt = 0; nt < 8; ++nt) {
    int c = nt * 16 + li;
    bias[nt] = (c < 64) ? bmu[c] : blv[c - 64];
  }

  f32x4 acc[8];
#pragma unroll
  for (int t = 0; t < 8; ++t) acc[t] = (f32x4){0.f, 0.f, 0.f, 0.f};

#pragma unroll
  for (int kk = 0; kk < 4; ++kk) {
    int ko = kk * 32 + quad * 8;
    bf16x8 a = *(const bf16x8*)&Xl[(m0 + li) * 136 + ko];
#pragma unroll
    for (int nt = 0; nt < 8; ++nt) {
      bf16x8 b = *(const bf16x8*)&Wl[(nt * 16 + li) * 136 + ko];
      acc[nt] = __builtin_amdgcn_mfma_f32_16x16x32_bf16(a, b, acc[nt], 0, 0, 0);
    }
  }
#pragma unroll
  for (int nt = 0; nt < 8; ++nt) {
    int col = nt * 16 + li;
#pragma unroll
    for (int r = 0; r < 4; ++r) {
      int gi = row0 + m0 + quad * 4 + r;
      if (gi < n) {
        float v = acc[nt][r] + bias[nt];
        if (col < 64) out[(size_t)gi * 64 + col] = v;              // mu
        else          out[(size_t)(n + gi) * 64 + (col - 64)] = v; // logvar
      }
    }
  }
}

extern "C" void kernel_launch(void* const* d_in, const int* in_sizes, int n_in,
                              void* d_out, int out_size, void* d_ws, size_t ws_size,
                              hipStream_t stream) {
  const float* x   = (const float*)d_in[0];
  const int*   ei  = (const int*)d_in[1];   // [2, E], row0 = src, row1 = dst
  const float* W1  = (const float*)d_in[3];
  const float* b1  = (const float*)d_in[4];
  const float* Wmu = (const float*)d_in[5];
  const float* bmu = (const float*)d_in[6];
  const float* Wlv = (const float*)d_in[7];
  const float* blv = (const float*)d_in[8];
  float* out = (float*)d_out;

  const int n = in_sizes[0] / 128;
  const int E = in_sizes[1] / 2;

  // workspace layout (float units)
  float* ws = (float*)d_ws;
  size_t p = 0;
  int* cnt    = (int*)(ws + p); p += (size_t)n * CSTRIDE;  // spread counters (64B apart)
  int* ocount = (int*)(ws + p); p += 1;
  p = (p + 3) & ~(size_t)3;  // 16B align
  int* ell    = (int*)(ws + p); p += (size_t)n * ELLK;     // TRANSPOSED: [ELLK][n]
  int2* ovf   = (int2*)(ws + p); p += (size_t)OCAP * 2;
  unsigned* A = (unsigned*)(ws + p); p += (size_t)(n + 1) * 64;  // +1: zero pad row
  unsigned* H = (unsigned*)(ws + p); p += (size_t)(n + 1) * 64;
  unsigned* G = (unsigned*)(ws + p); p += (size_t)n * 64;
  unsigned short* Wt1 = (unsigned short*)(ws + p); p += 8192;  // 128x128 bf16
  unsigned short* Wt2 = (unsigned short*)(ws + p); p += 8192;
  float* dnorm    = (float*)(ws + p); p += n;
  unsigned* mflag = (unsigned*)(ws + p); p += n;

  int nz4  = (n * CSTRIDE) / 4;        // uint4 count for counter zeroing
  int nbz  = (nz4 + 255) / 256;
  int eb   = (E + 1023) / 1024;        // 4 edges per thread
  int gblk = (n + 63) / 64;
  int sblk = (n + 3) / 4;              // one wave per node

  // 1) zero counters/ocount/pad-rows + weight transpose
  k_setup<<<nbz + 128, 256, 0, stream>>>(W1, Wmu, Wlv, Wt1, Wt2, (uint4*)cnt, ocount,
                                         A, H, nz4, nbz, n);
  // 2) ELL build (transposed planes, 4-deep atomic pipelining)
  k_fill<<<eb, 256, 0, stream>>>(ei, cnt, ell, ovf, ocount, E, n);
  // 3) A = bf16(dis_i * (x @ W1)) -- rows pre-scaled; emits dnorm/mflag as side product
  k_gemm1<<<gblk, 256, 0, stream>>>(x, Wt1, cnt, (unsigned short*)A, dnorm, mflag, n);
  // 4) layer 1: H = bf16(dis_i * relu(dis_i * sum + b1))  (pre-scaled for layer 2)
  k_spmm<true><<<sblk, 256, 0, stream>>>(mflag, dnorm, ell, ovf, ocount, A, H,
                                         (const float2*)b1, n);
  // 5) layer 2: G = bf16(dis_i * sum)
  k_spmm<false><<<sblk, 256, 0, stream>>>(mflag, dnorm, ell, ovf, ocount, H, G, nullptr, n);
  // 6) out = [G@Wmu+bmu | G@Wlv+blv]
  k_gemm2_mfma<<<gblk, 256, 0, stream>>>((const unsigned short*)G, Wt2, bmu, blv, out, n);
}